// Round 1
// baseline (412.580 us; speedup 1.0000x reference)
//
#include <hip/hip_runtime.h>
#include <hip/hip_bf16.h>

#define D_MODEL 2048
#define NQH 32
#define NKVH 8
#define HD 64
#define SEQ 2048
#define BATCH 2
#define MTOT (BATCH * SEQ) // 4096

typedef __attribute__((ext_vector_type(8))) short short8;
typedef __attribute__((ext_vector_type(4))) float floatx4;

static __device__ inline short f2bs(float x) {
  union { __hip_bfloat16 h; short s; } u;
  u.h = __float2bfloat16(x);
  return u.s;
}

// ---------------- fp32 -> bf16 elementwise (vectorized) ----------------
__global__ __launch_bounds__(256) void convx_k(const float* __restrict__ x,
                                               __hip_bfloat16* __restrict__ xb,
                                               int n4) {
  int i = blockIdx.x * 256 + threadIdx.x;
  int stride = gridDim.x * 256;
  for (; i < n4; i += stride) {
    float4 v = reinterpret_cast<const float4*>(x)[i];
    union { __hip_bfloat16 h[4]; uint2 u; } cv;
    cv.h[0] = __float2bfloat16(v.x);
    cv.h[1] = __float2bfloat16(v.y);
    cv.h[2] = __float2bfloat16(v.z);
    cv.h[3] = __float2bfloat16(v.w);
    reinterpret_cast<uint2*>(xb)[i] = cv.u;
  }
}

// ---------------- W [K][N] fp32  ->  W^T [N][K] bf16 ----------------
__global__ __launch_bounds__(256) void transw_k(const float* __restrict__ W,
                                                __hip_bfloat16* __restrict__ Wt,
                                                int Kd, int Nd) {
  __shared__ float t[32][33];
  int n0 = blockIdx.x * 32, k0 = blockIdx.y * 32;
  int tx = threadIdx.x, ty = threadIdx.y;
#pragma unroll
  for (int j = 0; j < 32; j += 8)
    t[ty + j][tx] = W[(size_t)(k0 + ty + j) * Nd + n0 + tx];
  __syncthreads();
#pragma unroll
  for (int j = 0; j < 32; j += 8)
    Wt[(size_t)(n0 + ty + j) * Kd + k0 + tx] = __float2bfloat16(t[tx][ty + j]);
}

// ---------------- GEMM  C[m][n] = sum_k A[m][k] * Bt[n][k] ----------------
// MODE 0: fp32 out to Cf [MTOT][2048]
// MODE 1: fused QKV epilogue (bf16 scatter; Q scaled by 1/8; V transposed)
template <int MODE>
__global__ __launch_bounds__(256) void gemm_bt_k(
    const __hip_bfloat16* __restrict__ A,
    const __hip_bfloat16* __restrict__ B0,
    const __hip_bfloat16* __restrict__ B1,
    const __hip_bfloat16* __restrict__ B2,
    float* __restrict__ Cf,
    __hip_bfloat16* __restrict__ O0,
    __hip_bfloat16* __restrict__ O1,
    __hip_bfloat16* __restrict__ O2) {
  constexpr int Kd = D_MODEL;
  const int tid = threadIdx.x;
  const int m0 = blockIdx.y * 128;
  const int n0 = blockIdx.x * 128;

  const __hip_bfloat16* Bt;
  if (MODE == 0) {
    Bt = B0 + (size_t)n0 * Kd;
  } else {
    if (n0 < 2048) Bt = B0 + (size_t)n0 * Kd;
    else if (n0 < 2560) Bt = B1 + (size_t)(n0 - 2048) * Kd;
    else Bt = B2 + (size_t)(n0 - 2560) * Kd;
  }
  const __hip_bfloat16* Ab = A + (size_t)m0 * Kd;

  __shared__ short As[128 * 40];
  __shared__ short Bs[128 * 40];

  const int w = tid >> 6, l = tid & 63;
  const int wr = w >> 1, wc = w & 1;
  const int lc = l & 15, l4 = l >> 4;

  floatx4 acc[4][4] = {};

  const int r0 = tid >> 2, kc0 = (tid & 3) << 3;

  for (int kt = 0; kt < Kd; kt += 32) {
    short8 a0 = *reinterpret_cast<const short8*>(Ab + (size_t)r0 * Kd + kt + kc0);
    short8 a1 = *reinterpret_cast<const short8*>(Ab + (size_t)(r0 + 64) * Kd + kt + kc0);
    short8 b0 = *reinterpret_cast<const short8*>(Bt + (size_t)r0 * Kd + kt + kc0);
    short8 b1 = *reinterpret_cast<const short8*>(Bt + (size_t)(r0 + 64) * Kd + kt + kc0);
    *reinterpret_cast<short8*>(&As[r0 * 40 + kc0]) = a0;
    *reinterpret_cast<short8*>(&As[(r0 + 64) * 40 + kc0]) = a1;
    *reinterpret_cast<short8*>(&Bs[r0 * 40 + kc0]) = b0;
    *reinterpret_cast<short8*>(&Bs[(r0 + 64) * 40 + kc0]) = b1;
    __syncthreads();

    short8 af[4], bf[4];
#pragma unroll
    for (int mi = 0; mi < 4; ++mi)
      af[mi] = *reinterpret_cast<const short8*>(&As[(wr * 64 + mi * 16 + lc) * 40 + l4 * 8]);
#pragma unroll
    for (int ni = 0; ni < 4; ++ni)
      bf[ni] = *reinterpret_cast<const short8*>(&Bs[(wc * 64 + ni * 16 + lc) * 40 + l4 * 8]);
#pragma unroll
    for (int mi = 0; mi < 4; ++mi)
#pragma unroll
      for (int ni = 0; ni < 4; ++ni)
        acc[mi][ni] = __builtin_amdgcn_mfma_f32_16x16x32_bf16(af[mi], bf[ni], acc[mi][ni], 0, 0, 0);
    __syncthreads();
  }

  // epilogue: C/D layout col = lane&15, row = (lane>>4)*4 + i
#pragma unroll
  for (int mi = 0; mi < 4; ++mi)
#pragma unroll
    for (int ni = 0; ni < 4; ++ni)
#pragma unroll
      for (int i = 0; i < 4; ++i) {
        int m = m0 + wr * 64 + mi * 16 + l4 * 4 + i;
        int ncol = n0 + wc * 64 + ni * 16 + lc;
        float v = acc[mi][ni][i];
        if (MODE == 0) {
          Cf[(size_t)m * 2048 + ncol] = v;
        } else {
          int bb = m >> 11, s = m & 2047;
          if (ncol < 2048) {
            int h = ncol >> 6, dd = ncol & 63;
            O0[(((size_t)bb * NQH + h) * SEQ + s) * HD + dd] = __float2bfloat16(v * 0.125f);
          } else if (ncol < 2560) {
            int c2 = ncol - 2048;
            int h = c2 >> 6, dd = c2 & 63;
            O1[(((size_t)bb * NKVH + h) * SEQ + s) * HD + dd] = __float2bfloat16(v);
          } else {
            int c2 = ncol - 2560;
            int h = c2 >> 6, dd = c2 & 63;
            O2[(((size_t)bb * NKVH + h) * HD + dd) * SEQ + s] = __float2bfloat16(v);
          }
        }
      }
}

// ---------------- Flash attention ----------------
// grid (S/128, NQH, B), 256 threads. Q pre-scaled by 1/8 at projection.
// Qb [b][h][s][d], Kb [b][kh][s][d], Vtb [b][kh][d][s]; out Ao [b][s][h*64+d] bf16
__global__ __launch_bounds__(256) void attn_k(const __hip_bfloat16* __restrict__ Qb,
                                              const __hip_bfloat16* __restrict__ Kb,
                                              const __hip_bfloat16* __restrict__ Vtb,
                                              __hip_bfloat16* __restrict__ Ao) {
  __shared__ short Qs[128 * 72];
  __shared__ short Ks[64 * 72];
  __shared__ short Vs[64 * 72];
  __shared__ short Ps[4 * 32 * 72];

  const int qt = blockIdx.x, h = blockIdx.y, b = blockIdx.z;
  const int kh = h >> 2;
  const int tid = threadIdx.x, w = tid >> 6, l = tid & 63;
  const int lc = l & 15, l4 = l >> 4;

  const __hip_bfloat16* Qp = Qb + (((size_t)b * NQH + h) * SEQ + qt * 128) * HD;
  const __hip_bfloat16* Kp = Kb + (((size_t)b * NKVH + kh) * SEQ) * HD;
  const __hip_bfloat16* Vp = Vtb + (((size_t)b * NKVH + kh) * HD) * SEQ;

  // stage Q tile [128][64] -> Qs stride 72
#pragma unroll
  for (int it = 0; it < 4; ++it) {
    int c = tid + it * 256;
    int r = c >> 3, d0 = (c & 7) << 3;
    *reinterpret_cast<short8*>(&Qs[r * 72 + d0]) =
        *reinterpret_cast<const short8*>(Qp + r * HD + d0);
  }

  floatx4 acc[2][4] = {};
  float mr[2][4], lr[2][4];
#pragma unroll
  for (int mi = 0; mi < 2; ++mi)
#pragma unroll
    for (int i = 0; i < 4; ++i) { mr[mi][i] = -1e30f; lr[mi][i] = 0.0f; }

  short* Pw = Ps + w * 32 * 72;

  for (int kb = 0; kb < SEQ / 64; ++kb) {
    // stage K [64][64] and V^T slice [64][64]
#pragma unroll
    for (int it = 0; it < 2; ++it) {
      int c = tid + it * 256;
      int r = c >> 3, d0 = (c & 7) << 3;
      *reinterpret_cast<short8*>(&Ks[r * 72 + d0]) =
          *reinterpret_cast<const short8*>(Kp + (size_t)(kb * 64 + r) * HD + d0);
      *reinterpret_cast<short8*>(&Vs[r * 72 + d0]) =
          *reinterpret_cast<const short8*>(Vp + (size_t)r * SEQ + kb * 64 + d0);
    }
    __syncthreads();

    // scores: rows = wave's 32 q-rows, cols = 64 kv
    floatx4 sf[2][4] = {};
    short8 qa[2][2], kf[4][2];
#pragma unroll
    for (int mi = 0; mi < 2; ++mi)
#pragma unroll
      for (int ks = 0; ks < 2; ++ks)
        qa[mi][ks] = *reinterpret_cast<const short8*>(&Qs[(w * 32 + mi * 16 + lc) * 72 + ks * 32 + l4 * 8]);
#pragma unroll
    for (int ni = 0; ni < 4; ++ni)
#pragma unroll
      for (int ks = 0; ks < 2; ++ks)
        kf[ni][ks] = *reinterpret_cast<const short8*>(&Ks[(ni * 16 + lc) * 72 + ks * 32 + l4 * 8]);
#pragma unroll
    for (int mi = 0; mi < 2; ++mi)
#pragma unroll
      for (int ni = 0; ni < 4; ++ni)
#pragma unroll
        for (int ks = 0; ks < 2; ++ks)
          sf[mi][ni] = __builtin_amdgcn_mfma_f32_16x16x32_bf16(qa[mi][ks], kf[ni][ks], sf[mi][ni], 0, 0, 0);

    // online softmax (row stats per (mi,i); cols spread over lanes 0..15 group)
#pragma unroll
    for (int mi = 0; mi < 2; ++mi)
#pragma unroll
      for (int i = 0; i < 4; ++i) {
        float mx = fmaxf(fmaxf(sf[mi][0][i], sf[mi][1][i]), fmaxf(sf[mi][2][i], sf[mi][3][i]));
#pragma unroll
        for (int d = 1; d < 16; d <<= 1) mx = fmaxf(mx, __shfl_xor(mx, d));
        float nm = fmaxf(mr[mi][i], mx);
        float scl = __expf(mr[mi][i] - nm);
        float ps = 0.0f;
#pragma unroll
        for (int ni = 0; ni < 4; ++ni) {
          float pv = __expf(sf[mi][ni][i] - nm);
          sf[mi][ni][i] = pv;
          ps += pv;
        }
#pragma unroll
        for (int d = 1; d < 16; d <<= 1) ps += __shfl_xor(ps, d);
        lr[mi][i] = lr[mi][i] * scl + ps;
        mr[mi][i] = nm;
#pragma unroll
        for (int ni = 0; ni < 4; ++ni) acc[mi][ni][i] *= scl;
      }

    // P (C-frag layout) -> LDS (A-frag layout source)
#pragma unroll
    for (int mi = 0; mi < 2; ++mi)
#pragma unroll
      for (int i = 0; i < 4; ++i) {
        int row = mi * 16 + l4 * 4 + i;
#pragma unroll
        for (int ni = 0; ni < 4; ++ni)
          Pw[row * 72 + ni * 16 + lc] = f2bs(sf[mi][ni][i]);
      }

    // PV
    short8 vf[4][2];
#pragma unroll
    for (int ni = 0; ni < 4; ++ni)
#pragma unroll
      for (int ks = 0; ks < 2; ++ks)
        vf[ni][ks] = *reinterpret_cast<const short8*>(&Vs[(ni * 16 + lc) * 72 + ks * 32 + l4 * 8]);
#pragma unroll
    for (int mi = 0; mi < 2; ++mi)
#pragma unroll
      for (int ks = 0; ks < 2; ++ks) {
        short8 pa = *reinterpret_cast<const short8*>(&Pw[(mi * 16 + lc) * 72 + ks * 32 + l4 * 8]);
#pragma unroll
        for (int ni = 0; ni < 4; ++ni)
          acc[mi][ni] = __builtin_amdgcn_mfma_f32_16x16x32_bf16(pa, vf[ni][ks], acc[mi][ni], 0, 0, 0);
      }
    __syncthreads();
  }

  // epilogue: normalize and store bf16 to [b][s][h*64+dd]
#pragma unroll
  for (int mi = 0; mi < 2; ++mi)
#pragma unroll
    for (int i = 0; i < 4; ++i) {
      float inv = 1.0f / lr[mi][i];
      int r = qt * 128 + w * 32 + mi * 16 + l4 * 4 + i;
#pragma unroll
      for (int ni = 0; ni < 4; ++ni) {
        float v = acc[mi][ni][i] * inv;
        Ao[((size_t)b * SEQ + r) * D_MODEL + h * HD + ni * 16 + lc] = __float2bfloat16(v);
      }
    }
}

// ---------------- host ----------------
extern "C" void kernel_launch(void* const* d_in, const int* in_sizes, int n_in,
                              void* d_out, int out_size, void* d_ws, size_t ws_size,
                              hipStream_t stream) {
  const float* x  = (const float*)d_in[0];
  const float* Wq = (const float*)d_in[1];
  const float* Wk = (const float*)d_in[2];
  const float* Wv = (const float*)d_in[3];
  const float* Wo = (const float*)d_in[4];
  float* out = (float*)d_out;

  __hip_bfloat16* p = (__hip_bfloat16*)d_ws;
  __hip_bfloat16* xb  = p;                 // 4096*2048
  __hip_bfloat16* Wqt = xb  + (size_t)MTOT * D_MODEL;        // 2048*2048
  __hip_bfloat16* Wkt = Wqt + (size_t)D_MODEL * D_MODEL;     // 512*2048
  __hip_bfloat16* Wvt = Wkt + (size_t)512 * D_MODEL;         // 512*2048
  __hip_bfloat16* Wot = Wvt + (size_t)512 * D_MODEL;         // 2048*2048
  __hip_bfloat16* Qb  = Wot + (size_t)D_MODEL * D_MODEL;     // 2*32*2048*64
  __hip_bfloat16* Kb  = Qb  + (size_t)MTOT * D_MODEL;        // 2*8*2048*64
  __hip_bfloat16* Vtb = Kb  + (size_t)BATCH * NKVH * SEQ * HD;
  __hip_bfloat16* Ab  = Vtb + (size_t)BATCH * NKVH * SEQ * HD; // 4096*2048

  convx_k<<<2048, 256, 0, stream>>>(x, xb, MTOT * D_MODEL / 4);
  transw_k<<<dim3(D_MODEL / 32, D_MODEL / 32), dim3(32, 8), 0, stream>>>(Wq, Wqt, D_MODEL, D_MODEL);
  transw_k<<<dim3(512 / 32, D_MODEL / 32), dim3(32, 8), 0, stream>>>(Wk, Wkt, D_MODEL, 512);
  transw_k<<<dim3(512 / 32, D_MODEL / 32), dim3(32, 8), 0, stream>>>(Wv, Wvt, D_MODEL, 512);
  transw_k<<<dim3(D_MODEL / 32, D_MODEL / 32), dim3(32, 8), 0, stream>>>(Wo, Wot, D_MODEL, D_MODEL);

  // fused QKV projection: N = 2048 (Q) + 512 (K) + 512 (V) = 3072
  gemm_bt_k<1><<<dim3(24, MTOT / 128), 256, 0, stream>>>(xb, Wqt, Wkt, Wvt,
                                                         nullptr, Qb, Kb, Vtb);
  attn_k<<<dim3(SEQ / 128, NQH, BATCH), 256, 0, stream>>>(Qb, Kb, Vtb, Ab);
  // output projection -> fp32
  gemm_bt_k<0><<<dim3(D_MODEL / 128, MTOT / 128), 256, 0, stream>>>(Ab, Wot, nullptr, nullptr,
                                                                    out, nullptr, nullptr, nullptr);
}